// Round 16
// baseline (187.848 us; speedup 1.0000x reference)
//
#include <hip/hip_runtime.h>

#define NROWS 16384
#define M2    32768   // 2N stacked
#define TT    128     // 256-row strips of the stacked matrix
#define HID   512
#define PROJ  128

constexpr float SCALE_L2E = 2.8853900817779268f; // log2(e)/tau, tau=0.5
constexpr float E2        = 7.38905609893065f;   // exp(1/tau) = diag term

typedef float f32x2   __attribute__((ext_vector_type(2)));
typedef float f32x4   __attribute__((ext_vector_type(4)));
typedef short bf16x8  __attribute__((ext_vector_type(8)));
typedef int   i32x8   __attribute__((ext_vector_type(8)));

__device__ inline short f2bf(float x) {
  union { float f; unsigned u; } v; v.f = x;
  unsigned r = v.u + 0x7fffu + ((v.u >> 16) & 1u); // RNE
  return (short)(r >> 16);
}
__device__ inline unsigned char f2fp8(float x) {
  return (unsigned char)(__builtin_amdgcn_cvt_pk_fp8_f32(x, x, 0, false) & 0xff);
}
// packed f32->bf16 RNE, lo = a, hi = b (v_cvt_pk_bf16_f32)
__device__ inline unsigned cvtpk_bf16(float a, float b) {
  unsigned r;
  asm("v_cvt_pk_bf16_f32 %0, %1, %2" : "=v"(r) : "v"(a), "v"(b));
  return r;
}

// ---- prep: W1 (512x128) -> W1t bf16 (128x512); W2 (128x128) -> W2t bf16 (128x128)
__global__ void kprep(const float* __restrict__ W1, const float* __restrict__ W2,
                      short* __restrict__ W1t, short* __restrict__ W2t) {
  int stride = gridDim.x * blockDim.x;
  for (int idx = blockIdx.x * blockDim.x + threadIdx.x; idx < 128 * 512; idx += stride) {
    int n = idx >> 9, k = idx & 511;
    W1t[idx] = f2bf(W1[k * 128 + n]);
  }
  for (int idx = blockIdx.x * blockDim.x + threadIdx.x; idx < 128 * 128; idx += stride) {
    int n = idx >> 7, k = idx & 127;
    W2t[idx] = f2bf(W2[k * 128 + n]);
  }
}

// ---- FUSED projection + u.v dot (R14, proven: tail 62->48us).
// 256 blocks x 512 thr; waves 0-3: z1 rows, waves 4-7: z2 same rows.
// After GEMM2+normalize, u-waves park nu in LDS (aliasing dead h-tiles,
// rotated layout); v-waves compute s[i] = nu_i . nv_i.
__global__ __launch_bounds__(512) void kproj(const float* __restrict__ z1,
                                             const float* __restrict__ z2,
                                             const short* __restrict__ W1t,
                                             const float* __restrict__ b1,
                                             const short* __restrict__ W2t,
                                             const float* __restrict__ b2,
                                             unsigned char* __restrict__ nnf,
                                             unsigned char* __restrict__ nsf,
                                             float* __restrict__ sv) {
  __shared__ short hls[2][64 * 128];   // 32KB: two swizzled h tiles (u, v)
  int wave = threadIdx.x >> 6, lane = threadIdx.x & 63;
  int lr = lane & 15, lg = lane >> 4;
  int uw = wave & 3, isV = wave >> 2;
  const float* z = isV ? z2 : z1;
  int rbase = blockIdx.x * 64 + uw * 16;          // row block (within 16384)
  const float* zrow = z + (size_t)(rbase + lr) * HID;
  short* hbase = hls[isV];

  // ---- GEMM1
  f32x4 acc[8];
#pragma unroll
  for (int ct = 0; ct < 8; ++ct) acc[ct] = (f32x4){0.f, 0.f, 0.f, 0.f};

  for (int kc = 0; kc < HID / 32; ++kc) {
    int kof = kc * 32 + lg * 8;
    f32x4 za = *(const f32x4*)(zrow + kof);
    f32x4 zb = *(const f32x4*)(zrow + kof + 4);
    union { unsigned u[4]; bf16x8 v; } af;
    af.u[0] = cvtpk_bf16(za[0], za[1]);
    af.u[1] = cvtpk_bf16(za[2], za[3]);
    af.u[2] = cvtpk_bf16(zb[0], zb[1]);
    af.u[3] = cvtpk_bf16(zb[2], zb[3]);
#pragma unroll
    for (int ct = 0; ct < 8; ++ct) {
      bf16x8 b = *(const bf16x8*)(W1t + (ct * 16 + lr) * HID + kof);
      acc[ct] = __builtin_amdgcn_mfma_f32_16x16x32_bf16(af.v, b, acc[ct], 0, 0, 0);
    }
  }
  // bias + ELU -> swizzled LDS (chunk^(row&15) pattern, matches GEMM2 reads)
#pragma unroll
  for (int ct = 0; ct < 8; ++ct) {
    int col = ct * 16 + lr;
    float bias = b1[col];
#pragma unroll
    for (int q = 0; q < 4; ++q) {
      int lrow = uw * 16 + lg * 4 + q;
      float x = acc[ct][q] + bias;
      x = x > 0.f ? x : (__builtin_amdgcn_exp2f(x * 1.44269504088896f) - 1.0f);
      int sw = (col >> 3) ^ (lrow & 15);
      hbase[lrow * 128 + sw * 8 + (col & 7)] = f2bf(x);
    }
  }
  __syncthreads();

  // ---- GEMM2: A row = uw*16 + lr (local), chunk (kc*4+lg)^lr
  int lrow2 = uw * 16 + lr;
  f32x4 acc2[8];
#pragma unroll
  for (int ct = 0; ct < 8; ++ct) acc2[ct] = (f32x4){0.f, 0.f, 0.f, 0.f};

#pragma unroll
  for (int kc = 0; kc < PROJ / 32; ++kc) {
    bf16x8 a = *(const bf16x8*)&hbase[lrow2 * 128 + (((kc * 4 + lg) ^ lr) << 3)];
#pragma unroll
    for (int ct = 0; ct < 8; ++ct) {
      bf16x8 b = *(const bf16x8*)(W2t + (ct * 16 + lr) * PROJ + kc * 32 + lg * 8);
      acc2[ct] = __builtin_amdgcn_mfma_f32_16x16x32_bf16(a, b, acc2[ct], 0, 0, 0);
    }
  }
#pragma unroll
  for (int ct = 0; ct < 8; ++ct) {
    float bias = b2[ct * 16 + lr];
#pragma unroll
    for (int q = 0; q < 4; ++q) acc2[ct][q] += bias;
  }
  float inv[4];
#pragma unroll
  for (int q = 0; q < 4; ++q) {
    float s = 0.f;
#pragma unroll
    for (int ct = 0; ct < 8; ++ct) s += acc2[ct][q] * acc2[ct][q];
    s += __shfl_xor(s, 1); s += __shfl_xor(s, 2);
    s += __shfl_xor(s, 4); s += __shfl_xor(s, 8);
    inv[q] = 1.f / fmaxf(sqrtf(s), 1e-12f);
  }
  // normalize in place; write fp8 outputs
  int rglob0 = rbase + (isV ? NROWS : 0);
#pragma unroll
  for (int ct = 0; ct < 8; ++ct) {
    int col = ct * 16 + lr;
#pragma unroll
    for (int q = 0; q < 4; ++q) {
      float v = acc2[ct][q] * inv[q];
      acc2[ct][q] = v;
      int row = rglob0 + lg * 4 + q;
      nnf[(size_t)row * PROJ + col] = f2fp8(v);
      nsf[(size_t)row * PROJ + col] = f2fp8(v * SCALE_L2E);
    }
  }

  // ---- s_i = nu_i . nv_i : park nu in LDS (alias dead h-tiles), v-waves dot.
  __syncthreads();                 // all GEMM2 hls reads done before aliasing
  float* un = (float*)hls;         // [64][128] with per-row rotation by 4*row
  if (!isV) {
#pragma unroll
    for (int ct = 0; ct < 8; ++ct) {
      int col = ct * 16 + lr;
#pragma unroll
      for (int q = 0; q < 4; ++q) {
        int lrow = uw * 16 + lg * 4 + q;
        un[lrow * 128 + ((col + (lrow << 2)) & 127)] = acc2[ct][q];
      }
    }
  }
  __syncthreads();
  if (isV) {
    float pd[4] = {0.f, 0.f, 0.f, 0.f};
#pragma unroll
    for (int ct = 0; ct < 8; ++ct) {
      int col = ct * 16 + lr;
#pragma unroll
      for (int q = 0; q < 4; ++q) {
        int lrow = uw * 16 + lg * 4 + q;
        pd[q] += un[lrow * 128 + ((col + (lrow << 2)) & 127)] * acc2[ct][q];
      }
    }
#pragma unroll
    for (int q = 0; q < 4; ++q) {
      float v = pd[q];
      v += __shfl_xor(v, 1); v += __shfl_xor(v, 2);
      v += __shfl_xor(v, 4); v += __shfl_xor(v, 8);
      if (lr == 0) sv[rbase + lg * 4 + q] = v;
    }
  }
}

// ---- symmetric similarity, MX-scaled fp8 (unit scales), LDS-staged, PIPELINED.
// Inner loop = EXACT R11/R13 body (proven 126us, VGPR 36, zero spill). FROZEN:
//  - R10 per-jt LDS atomicAdd: serialized RMW -> 411us
//  - R12 col-pair ILP: occupancy 62->42% -> 149us
//  - R14 skewed pipeline: +live state -> compiler spill loop -> 257us
// R16: LDS 40960->36864 (colbuf halved to [8][128], flushed twice) to fit
// 4 blocks/CU (R10 datapoint: LDS 34816 -> occupancy 68% vs 62% at 40960).
// jt loop: unroll 2 + named cur/nxt (full unroll spills -- R5); bounds (512,4).
__global__ __launch_bounds__(512, 4) void ksim16(const unsigned char* __restrict__ nnf,
                                                 const unsigned char* __restrict__ nsf,
                                                 float* __restrict__ d) {
  __shared__ long BtL[256 * 16];       // 32KB fp8 tile, 16 longs (8B slots) per row
  __shared__ float colbuf[8][128];     // 4KB per-wave colsum partials (half tile)

  int tid = threadIdx.x;
  int w = tid >> 6, lane = tid & 63;
  int lr = lane & 15, lg = lane >> 4;

  // triangular decode: tile t -> (ib, jb), jb >= ib
  int t = blockIdx.x;
  float ff = (float)((2 * TT + 1) * (2 * TT + 1) - 8 * t);
  int ib = (int)(((float)(2 * TT + 1) - sqrtf(ff)) * 0.5f);
  if (ib < 0) ib = 0;
  if (ib > TT - 1) ib = TT - 1;
  while (ib > 0 && ib * (2 * TT - ib + 1) / 2 > t) --ib;
  while ((ib + 1) * (2 * TT - ib) / 2 <= t) ++ib;
  int jb = ib + (t - ib * (2 * TT - ib + 1) / 2);
  bool diag = (ib == jb);

  int i0 = ib * 256 + w * 32;

  // A-fragments: rows i0+rb*16+lr of scaled fp8; lane holds bytes [lg*32, +32)
  i32x8 a[2];
#pragma unroll
  for (int rb = 0; rb < 2; ++rb)
    a[rb] = *(const i32x8*)(nsf + (size_t)(i0 + rb * 16 + lr) * PROJ + lg * 32);

  // stage B tile: 256 rows x 16 slots(8B); thread loads 8, writes swizzled
  {
    int slot = tid & 15, row0 = tid >> 4;   // row0 0..31
    const long* bsrc = (const long*)(nnf + (size_t)(jb * 256 + row0) * PROJ) + slot;
    long st[8];
#pragma unroll
    for (int r = 0; r < 8; ++r) st[r] = bsrc[(size_t)r * 32 * 16];
#pragma unroll
    for (int r = 0; r < 8; ++r) {
      int row = r * 32 + row0;
      BtL[row * 16 + (slot ^ (row & 15))] = st[r];
    }
  }
  __syncthreads();

  f32x4 rs0 = (f32x4){0.f, 0.f, 0.f, 0.f};
  f32x4 rs1 = (f32x4){0.f, 0.f, 0.f, 0.f};

  // B addresses: row = jt*16+lr; slot s holds data slot s^(row&15) = s^lr.
  const char* bb = (const char*)BtL + lr * 128;
  unsigned xo0 = (unsigned)(((lg * 4 + 0) ^ lr) << 3);
  unsigned xo1 = (unsigned)(((lg * 4 + 1) ^ lr) << 3);
  unsigned xo2 = (unsigned)(((lg * 4 + 2) ^ lr) << 3);
  unsigned xo3 = (unsigned)(((lg * 4 + 3) ^ lr) << 3);

  union BFrag { long h[4]; i32x8 v; };

  // prologue: load jt=0's fragment
  BFrag cur;
  cur.h[0] = *(const long*)(bb + xo0);
  cur.h[1] = *(const long*)(bb + xo1);
  cur.h[2] = *(const long*)(bb + xo2);
  cur.h[3] = *(const long*)(bb + xo3);

#pragma unroll 1
  for (int half = 0; half < 2; ++half) {
#pragma unroll 2
    for (int jt8 = 0; jt8 < 8; ++jt8) {
      // prefetch next (global jt=15 reads colbuf-region garbage, in-bounds)
      const char* bn = bb + 2048;
      BFrag nxt;
      nxt.h[0] = *(const long*)(bn + xo0);
      nxt.h[1] = *(const long*)(bn + xo1);
      nxt.h[2] = *(const long*)(bn + xo2);
      nxt.h[3] = *(const long*)(bn + xo3);

      f32x4 c0 = (f32x4){0.f, 0.f, 0.f, 0.f};
      f32x4 c1 = (f32x4){0.f, 0.f, 0.f, 0.f};
      c0 = __builtin_amdgcn_mfma_scale_f32_16x16x128_f8f6f4(a[0], cur.v, c0, 0, 0,
                                                            0, 0x7f7f7f7f, 0, 0x7f7f7f7f);
      c1 = __builtin_amdgcn_mfma_scale_f32_16x16x128_f8f6f4(a[1], cur.v, c1, 0, 0,
                                                            0, 0x7f7f7f7f, 0, 0x7f7f7f7f);

      f32x4 e0, e1;
#pragma unroll
      for (int q = 0; q < 4; ++q) {
        e0[q] = __builtin_amdgcn_exp2f(c0[q]);
        e1[q] = __builtin_amdgcn_exp2f(c1[q]);
      }
      rs0 += e0;              // v_pk_add_f32 x2
      rs1 += e1;
      f32x4 s4 = e0 + e1;     // v_pk_add_f32 x2
      f32x2 h2 = __builtin_shufflevector(s4, s4, 0, 1)
               + __builtin_shufflevector(s4, s4, 2, 3);  // v_pk_add_f32
      float cs = h2[0] + h2[1];
      // colsum partial over this wave's 32 rows for col (half*8+jt8)*16+lr
      cs += __shfl_xor(cs, 16);
      cs += __shfl_xor(cs, 32);
      if (lg == 0) colbuf[w][jt8 * 16 + lr] = cs;

      cur = nxt;
      bb = bn;
    }
    // flush this half's 128 columns: cross-wave reduce, one atomic per column
    __syncthreads();
    if (!diag && tid < 128) {
      float s = 0.f;
#pragma unroll
      for (int w2 = 0; w2 < 8; ++w2) s += colbuf[w2][tid];
      atomicAdd(&d[jb * 256 + half * 128 + tid], s);
    }
    __syncthreads();
  }

  // rowsums: reduce over the 16 lr lanes, one atomic instruction per wave
  float myval = 0.f;
#pragma unroll
  for (int rb = 0; rb < 2; ++rb)
#pragma unroll
    for (int q = 0; q < 4; ++q) {
      float v = (rb == 0) ? rs0[q] : rs1[q];
      v += __shfl_xor(v, 1); v += __shfl_xor(v, 2);
      v += __shfl_xor(v, 4); v += __shfl_xor(v, 8);
      if (lr == rb * 4 + q) myval = v;
    }
  if (lr < 8)
    atomicAdd(&d[i0 + (lr >> 2) * 16 + lg * 4 + (lr & 3)], myval);
}

// ---- final: per-row loss from d[] and s[], mean into d_out
__global__ __launch_bounds__(256) void kfinal(const float* __restrict__ sv,
                                              const float* __restrict__ d,
                                              float* __restrict__ out) {
  int wave = threadIdx.x >> 6, lane = threadIdx.x & 63;
  int i = blockIdx.x * 256 + threadIdx.x;

  float den1 = d[i] - E2;
  float den2 = d[NROWS + i] - E2;
  // 0.5*(l1+l2) = 0.5*(log den1 + log den2) - s/tau
  float li = 0.5f * (logf(den1) + logf(den2)) - sv[i] * 2.0f;

#pragma unroll
  for (int m = 1; m < 64; m <<= 1) li += __shfl_xor(li, m);
  __shared__ float ws4[4];
  if (lane == 0) ws4[wave] = li;
  __syncthreads();
  if (threadIdx.x == 0)
    atomicAdd(out, (ws4[0] + ws4[1] + ws4[2] + ws4[3]) * (1.f / (float)NROWS));
}

extern "C" void kernel_launch(void* const* d_in, const int* in_sizes, int n_in,
                              void* d_out, int out_size, void* d_ws, size_t ws_size,
                              hipStream_t stream) {
  (void)in_sizes; (void)n_in; (void)out_size; (void)ws_size;
  const float* z1 = (const float*)d_in[0];
  const float* z2 = (const float*)d_in[1];
  const float* W1 = (const float*)d_in[2];
  const float* b1 = (const float*)d_in[3];
  const float* W2 = (const float*)d_in[4];
  const float* b2 = (const float*)d_in[5];
  float* out = (float*)d_out;

  short* W1t = (short*)d_ws;                          // 128KB
  short* W2t = W1t + 128 * 512;                       // 32KB
  unsigned char* nnf = (unsigned char*)(W2t + 128 * 128);         // 4MB fp8
  unsigned char* nsf = nnf + (size_t)M2 * PROJ;                   // 4MB fp8
  float* d  = (float*)(nsf + (size_t)M2 * PROJ);      // 32768 f32
  float* sv = d + M2;                                 // 16384 f32

  hipMemsetAsync(d_out, 0, sizeof(float), stream);
  hipMemsetAsync(d, 0, (size_t)M2 * sizeof(float), stream);

  kprep<<<16, 256, 0, stream>>>(W1, W2, W1t, W2t);
  kproj<<<NROWS / 64, 512, 0, stream>>>(z1, z2, W1t, b1, W2t, b2, nnf, nsf, sv);
  ksim16<<<TT * (TT + 1) / 2, 512, 0, stream>>>(nnf, nsf, d);
  kfinal<<<NROWS / 256, 256, 0, stream>>>(sv, d, out);
}

// Round 17
// 175.509 us; speedup vs baseline: 1.0703x; 1.0703x over previous
//
#include <hip/hip_runtime.h>

#define NROWS 16384
#define M2    32768   // 2N stacked
#define TT    128     // 256-row strips of the stacked matrix
#define HID   512
#define PROJ  128

constexpr float SCALE_L2E = 2.8853900817779268f; // log2(e)/tau, tau=0.5
constexpr float E2        = 7.38905609893065f;   // exp(1/tau) = diag term

typedef float f32x2   __attribute__((ext_vector_type(2)));
typedef float f32x4   __attribute__((ext_vector_type(4)));
typedef short bf16x8  __attribute__((ext_vector_type(8)));
typedef int   i32x8   __attribute__((ext_vector_type(8)));

__device__ inline short f2bf(float x) {
  union { float f; unsigned u; } v; v.f = x;
  unsigned r = v.u + 0x7fffu + ((v.u >> 16) & 1u); // RNE
  return (short)(r >> 16);
}
__device__ inline unsigned char f2fp8(float x) {
  return (unsigned char)(__builtin_amdgcn_cvt_pk_fp8_f32(x, x, 0, false) & 0xff);
}
// packed f32->bf16 RNE, lo = a, hi = b (v_cvt_pk_bf16_f32)
__device__ inline unsigned cvtpk_bf16(float a, float b) {
  unsigned r;
  asm("v_cvt_pk_bf16_f32 %0, %1, %2" : "=v"(r) : "v"(a), "v"(b));
  return r;
}

// ---- prep: W1 (512x128) -> W1t bf16 (128x512); W2 (128x128) -> W2t bf16 (128x128)
__global__ void kprep(const float* __restrict__ W1, const float* __restrict__ W2,
                      short* __restrict__ W1t, short* __restrict__ W2t) {
  int stride = gridDim.x * blockDim.x;
  for (int idx = blockIdx.x * blockDim.x + threadIdx.x; idx < 128 * 512; idx += stride) {
    int n = idx >> 9, k = idx & 511;
    W1t[idx] = f2bf(W1[k * 128 + n]);
  }
  for (int idx = blockIdx.x * blockDim.x + threadIdx.x; idx < 128 * 128; idx += stride) {
    int n = idx >> 7, k = idx & 127;
    W2t[idx] = f2bf(W2[k * 128 + n]);
  }
}

// ---- FUSED projection + u.v dot (R14, proven: tail 62->48us).
// 256 blocks x 512 thr; waves 0-3: z1 rows, waves 4-7: z2 same rows.
// After GEMM2+normalize, u-waves park nu in LDS (aliasing dead h-tiles,
// rotated layout); v-waves compute s[i] = nu_i . nv_i.
__global__ __launch_bounds__(512) void kproj(const float* __restrict__ z1,
                                             const float* __restrict__ z2,
                                             const short* __restrict__ W1t,
                                             const float* __restrict__ b1,
                                             const short* __restrict__ W2t,
                                             const float* __restrict__ b2,
                                             unsigned char* __restrict__ nnf,
                                             unsigned char* __restrict__ nsf,
                                             float* __restrict__ sv) {
  __shared__ short hls[2][64 * 128];   // 32KB: two swizzled h tiles (u, v)
  int wave = threadIdx.x >> 6, lane = threadIdx.x & 63;
  int lr = lane & 15, lg = lane >> 4;
  int uw = wave & 3, isV = wave >> 2;
  const float* z = isV ? z2 : z1;
  int rbase = blockIdx.x * 64 + uw * 16;          // row block (within 16384)
  const float* zrow = z + (size_t)(rbase + lr) * HID;
  short* hbase = hls[isV];

  // ---- GEMM1
  f32x4 acc[8];
#pragma unroll
  for (int ct = 0; ct < 8; ++ct) acc[ct] = (f32x4){0.f, 0.f, 0.f, 0.f};

  for (int kc = 0; kc < HID / 32; ++kc) {
    int kof = kc * 32 + lg * 8;
    f32x4 za = *(const f32x4*)(zrow + kof);
    f32x4 zb = *(const f32x4*)(zrow + kof + 4);
    union { unsigned u[4]; bf16x8 v; } af;
    af.u[0] = cvtpk_bf16(za[0], za[1]);
    af.u[1] = cvtpk_bf16(za[2], za[3]);
    af.u[2] = cvtpk_bf16(zb[0], zb[1]);
    af.u[3] = cvtpk_bf16(zb[2], zb[3]);
#pragma unroll
    for (int ct = 0; ct < 8; ++ct) {
      bf16x8 b = *(const bf16x8*)(W1t + (ct * 16 + lr) * HID + kof);
      acc[ct] = __builtin_amdgcn_mfma_f32_16x16x32_bf16(af.v, b, acc[ct], 0, 0, 0);
    }
  }
  // bias + ELU -> swizzled LDS (chunk^(row&15) pattern, matches GEMM2 reads)
#pragma unroll
  for (int ct = 0; ct < 8; ++ct) {
    int col = ct * 16 + lr;
    float bias = b1[col];
#pragma unroll
    for (int q = 0; q < 4; ++q) {
      int lrow = uw * 16 + lg * 4 + q;
      float x = acc[ct][q] + bias;
      x = x > 0.f ? x : (__builtin_amdgcn_exp2f(x * 1.44269504088896f) - 1.0f);
      int sw = (col >> 3) ^ (lrow & 15);
      hbase[lrow * 128 + sw * 8 + (col & 7)] = f2bf(x);
    }
  }
  __syncthreads();

  // ---- GEMM2: A row = uw*16 + lr (local), chunk (kc*4+lg)^lr
  int lrow2 = uw * 16 + lr;
  f32x4 acc2[8];
#pragma unroll
  for (int ct = 0; ct < 8; ++ct) acc2[ct] = (f32x4){0.f, 0.f, 0.f, 0.f};

#pragma unroll
  for (int kc = 0; kc < PROJ / 32; ++kc) {
    bf16x8 a = *(const bf16x8*)&hbase[lrow2 * 128 + (((kc * 4 + lg) ^ lr) << 3)];
#pragma unroll
    for (int ct = 0; ct < 8; ++ct) {
      bf16x8 b = *(const bf16x8*)(W2t + (ct * 16 + lr) * PROJ + kc * 32 + lg * 8);
      acc2[ct] = __builtin_amdgcn_mfma_f32_16x16x32_bf16(a, b, acc2[ct], 0, 0, 0);
    }
  }
#pragma unroll
  for (int ct = 0; ct < 8; ++ct) {
    float bias = b2[ct * 16 + lr];
#pragma unroll
    for (int q = 0; q < 4; ++q) acc2[ct][q] += bias;
  }
  float inv[4];
#pragma unroll
  for (int q = 0; q < 4; ++q) {
    float s = 0.f;
#pragma unroll
    for (int ct = 0; ct < 8; ++ct) s += acc2[ct][q] * acc2[ct][q];
    s += __shfl_xor(s, 1); s += __shfl_xor(s, 2);
    s += __shfl_xor(s, 4); s += __shfl_xor(s, 8);
    inv[q] = 1.f / fmaxf(sqrtf(s), 1e-12f);
  }
  // normalize in place; write fp8 outputs
  int rglob0 = rbase + (isV ? NROWS : 0);
#pragma unroll
  for (int ct = 0; ct < 8; ++ct) {
    int col = ct * 16 + lr;
#pragma unroll
    for (int q = 0; q < 4; ++q) {
      float v = acc2[ct][q] * inv[q];
      acc2[ct][q] = v;
      int row = rglob0 + lg * 4 + q;
      nnf[(size_t)row * PROJ + col] = f2fp8(v);
      nsf[(size_t)row * PROJ + col] = f2fp8(v * SCALE_L2E);
    }
  }

  // ---- s_i = nu_i . nv_i : park nu in LDS (alias dead h-tiles), v-waves dot.
  __syncthreads();                 // all GEMM2 hls reads done before aliasing
  float* un = (float*)hls;         // [64][128] with per-row rotation by 4*row
  if (!isV) {
#pragma unroll
    for (int ct = 0; ct < 8; ++ct) {
      int col = ct * 16 + lr;
#pragma unroll
      for (int q = 0; q < 4; ++q) {
        int lrow = uw * 16 + lg * 4 + q;
        un[lrow * 128 + ((col + (lrow << 2)) & 127)] = acc2[ct][q];
      }
    }
  }
  __syncthreads();
  if (isV) {
    float pd[4] = {0.f, 0.f, 0.f, 0.f};
#pragma unroll
    for (int ct = 0; ct < 8; ++ct) {
      int col = ct * 16 + lr;
#pragma unroll
      for (int q = 0; q < 4; ++q) {
        int lrow = uw * 16 + lg * 4 + q;
        pd[q] += un[lrow * 128 + ((col + (lrow << 2)) & 127)] * acc2[ct][q];
      }
    }
#pragma unroll
    for (int q = 0; q < 4; ++q) {
      float v = pd[q];
      v += __shfl_xor(v, 1); v += __shfl_xor(v, 2);
      v += __shfl_xor(v, 4); v += __shfl_xor(v, 8);
      if (lr == 0) sv[rbase + lg * 4 + q] = v;
    }
  }
}

// ---- symmetric similarity, MX-scaled fp8 (unit scales), LDS-staged, PIPELINED.
// EXACT R11/R13/R15 body (proven 126us, VGPR 36, zero spill). FROZEN:
//  - R10 per-jt LDS atomicAdd: serialized RMW -> 411us
//  - R12 col-pair ILP: occupancy 62->42% -> 149us
//  - R14 skewed pipeline: +live state -> compiler spill loop -> 257us
//  - R16 colbuf-halving for occupancy: LDS was never the limiter -> 140us
// jt loop: unroll 2 + named cur/nxt (full unroll spills -- R5); bounds (512,4).
__global__ __launch_bounds__(512, 4) void ksim17(const unsigned char* __restrict__ nnf,
                                                 const unsigned char* __restrict__ nsf,
                                                 float* __restrict__ d) {
  __shared__ long BtL[256 * 16];       // 32KB fp8 tile, 16 longs (8B slots) per row
  __shared__ float colbuf[8][256];     // 8KB per-wave colsum partials

  int tid = threadIdx.x;
  int w = tid >> 6, lane = tid & 63;
  int lr = lane & 15, lg = lane >> 4;

  // triangular decode: tile t -> (ib, jb), jb >= ib
  int t = blockIdx.x;
  float ff = (float)((2 * TT + 1) * (2 * TT + 1) - 8 * t);
  int ib = (int)(((float)(2 * TT + 1) - sqrtf(ff)) * 0.5f);
  if (ib < 0) ib = 0;
  if (ib > TT - 1) ib = TT - 1;
  while (ib > 0 && ib * (2 * TT - ib + 1) / 2 > t) --ib;
  while ((ib + 1) * (2 * TT - ib) / 2 <= t) ++ib;
  int jb = ib + (t - ib * (2 * TT - ib + 1) / 2);
  bool diag = (ib == jb);

  int i0 = ib * 256 + w * 32;

  // A-fragments: rows i0+rb*16+lr of scaled fp8; lane holds bytes [lg*32, +32)
  i32x8 a[2];
#pragma unroll
  for (int rb = 0; rb < 2; ++rb)
    a[rb] = *(const i32x8*)(nsf + (size_t)(i0 + rb * 16 + lr) * PROJ + lg * 32);

  // stage B tile: 256 rows x 16 slots(8B); thread loads 8, writes swizzled
  {
    int slot = tid & 15, row0 = tid >> 4;   // row0 0..31
    const long* bsrc = (const long*)(nnf + (size_t)(jb * 256 + row0) * PROJ) + slot;
    long st[8];
#pragma unroll
    for (int r = 0; r < 8; ++r) st[r] = bsrc[(size_t)r * 32 * 16];
#pragma unroll
    for (int r = 0; r < 8; ++r) {
      int row = r * 32 + row0;
      BtL[row * 16 + (slot ^ (row & 15))] = st[r];
    }
  }
  __syncthreads();

  f32x4 rs0 = (f32x4){0.f, 0.f, 0.f, 0.f};
  f32x4 rs1 = (f32x4){0.f, 0.f, 0.f, 0.f};

  // B addresses: row = jt*16+lr; slot s holds data slot s^(row&15) = s^lr.
  const char* bb = (const char*)BtL + lr * 128;
  unsigned xo0 = (unsigned)(((lg * 4 + 0) ^ lr) << 3);
  unsigned xo1 = (unsigned)(((lg * 4 + 1) ^ lr) << 3);
  unsigned xo2 = (unsigned)(((lg * 4 + 2) ^ lr) << 3);
  unsigned xo3 = (unsigned)(((lg * 4 + 3) ^ lr) << 3);

  union BFrag { long h[4]; i32x8 v; };

  // prologue: load jt=0's fragment
  BFrag cur;
  cur.h[0] = *(const long*)(bb + xo0);
  cur.h[1] = *(const long*)(bb + xo1);
  cur.h[2] = *(const long*)(bb + xo2);
  cur.h[3] = *(const long*)(bb + xo3);

#pragma unroll 2
  for (int jt = 0; jt < 16; ++jt) {
    // prefetch jt+1 (jt=15 reads colbuf-region garbage, in-bounds, unused)
    const char* bn = bb + 2048;
    BFrag nxt;
    nxt.h[0] = *(const long*)(bn + xo0);
    nxt.h[1] = *(const long*)(bn + xo1);
    nxt.h[2] = *(const long*)(bn + xo2);
    nxt.h[3] = *(const long*)(bn + xo3);

    f32x4 c0 = (f32x4){0.f, 0.f, 0.f, 0.f};
    f32x4 c1 = (f32x4){0.f, 0.f, 0.f, 0.f};
    c0 = __builtin_amdgcn_mfma_scale_f32_16x16x128_f8f6f4(a[0], cur.v, c0, 0, 0,
                                                          0, 0x7f7f7f7f, 0, 0x7f7f7f7f);
    c1 = __builtin_amdgcn_mfma_scale_f32_16x16x128_f8f6f4(a[1], cur.v, c1, 0, 0,
                                                          0, 0x7f7f7f7f, 0, 0x7f7f7f7f);

    f32x4 e0, e1;
#pragma unroll
    for (int q = 0; q < 4; ++q) {
      e0[q] = __builtin_amdgcn_exp2f(c0[q]);
      e1[q] = __builtin_amdgcn_exp2f(c1[q]);
    }
    rs0 += e0;              // v_pk_add_f32 x2
    rs1 += e1;
    f32x4 s4 = e0 + e1;     // v_pk_add_f32 x2
    f32x2 h2 = __builtin_shufflevector(s4, s4, 0, 1)
             + __builtin_shufflevector(s4, s4, 2, 3);  // v_pk_add_f32
    float cs = h2[0] + h2[1];
    // colsum partial over this wave's 32 rows for col jt*16+lr
    cs += __shfl_xor(cs, 16);
    cs += __shfl_xor(cs, 32);
    if (lg == 0) colbuf[w][jt * 16 + lr] = cs;

    cur = nxt;
    bb = bn;
  }

  // rowsums: reduce over the 16 lr lanes, one atomic instruction per wave
  float myval = 0.f;
#pragma unroll
  for (int rb = 0; rb < 2; ++rb)
#pragma unroll
    for (int q = 0; q < 4; ++q) {
      float v = (rb == 0) ? rs0[q] : rs1[q];
      v += __shfl_xor(v, 1); v += __shfl_xor(v, 2);
      v += __shfl_xor(v, 4); v += __shfl_xor(v, 8);
      if (lr == rb * 4 + q) myval = v;
    }
  if (lr < 8)
    atomicAdd(&d[i0 + (lr >> 2) * 16 + lg * 4 + (lr & 3)], myval);

  // colsums: cross-wave reduce in LDS, then one atomic per column
  __syncthreads();
  if (!diag && tid < 256) {
    float s = 0.f;
#pragma unroll
    for (int w2 = 0; w2 < 8; ++w2) s += colbuf[w2][tid];
    atomicAdd(&d[jb * 256 + tid], s);
  }
}

// ---- final: per-row loss from d[] and s[], mean into d_out
__global__ __launch_bounds__(256) void kfinal(const float* __restrict__ sv,
                                              const float* __restrict__ d,
                                              float* __restrict__ out) {
  int wave = threadIdx.x >> 6, lane = threadIdx.x & 63;
  int i = blockIdx.x * 256 + threadIdx.x;

  float den1 = d[i] - E2;
  float den2 = d[NROWS + i] - E2;
  // 0.5*(l1+l2) = 0.5*(log den1 + log den2) - s/tau
  float li = 0.5f * (logf(den1) + logf(den2)) - sv[i] * 2.0f;

#pragma unroll
  for (int m = 1; m < 64; m <<= 1) li += __shfl_xor(li, m);
  __shared__ float ws4[4];
  if (lane == 0) ws4[wave] = li;
  __syncthreads();
  if (threadIdx.x == 0)
    atomicAdd(out, (ws4[0] + ws4[1] + ws4[2] + ws4[3]) * (1.f / (float)NROWS));
}

extern "C" void kernel_launch(void* const* d_in, const int* in_sizes, int n_in,
                              void* d_out, int out_size, void* d_ws, size_t ws_size,
                              hipStream_t stream) {
  (void)in_sizes; (void)n_in; (void)out_size; (void)ws_size;
  const float* z1 = (const float*)d_in[0];
  const float* z2 = (const float*)d_in[1];
  const float* W1 = (const float*)d_in[2];
  const float* b1 = (const float*)d_in[3];
  const float* W2 = (const float*)d_in[4];
  const float* b2 = (const float*)d_in[5];
  float* out = (float*)d_out;

  short* W1t = (short*)d_ws;                          // 128KB
  short* W2t = W1t + 128 * 512;                       // 32KB
  unsigned char* nnf = (unsigned char*)(W2t + 128 * 128);         // 4MB fp8
  unsigned char* nsf = nnf + (size_t)M2 * PROJ;                   // 4MB fp8
  float* d  = (float*)(nsf + (size_t)M2 * PROJ);      // 32768 f32
  float* sv = d + M2;                                 // 16384 f32

  hipMemsetAsync(d_out, 0, sizeof(float), stream);
  hipMemsetAsync(d, 0, (size_t)M2 * sizeof(float), stream);

  kprep<<<16, 256, 0, stream>>>(W1, W2, W1t, W2t);
  kproj<<<NROWS / 64, 512, 0, stream>>>(z1, z2, W1t, b1, W2t, b2, nnf, nsf, sv);
  ksim17<<<TT * (TT + 1) / 2, 512, 0, stream>>>(nnf, nsf, d);
  kfinal<<<NROWS / 256, 256, 0, stream>>>(sv, d, out);
}